// Round 3
// baseline (1724.229 us; speedup 1.0000x reference)
//
#include <hip/hip_runtime.h>

// Billeh column GLIF forward — persistent kernel, event-driven quiet path.
//
// Round-2 post-mortem: 27us/step came from (a) 400K uncached MALL ops/step on
// rec_in even when nothing spiked, (b) 391 pollers + 391 RMWs saturating one
// barrier cacheline. This version:
//  - piggybacks a global "any spike" count on the barrier word; quiet steps do
//    ZERO uncached per-thread ops and no vmcnt drain,
//  - two-level barrier: single master polls arrivals (RMW line), publishes a
//    release word on a separate 64B line polled by 97 leaders with backoff,
//  - spiking steps (rare) use a ballot bitmask + full-E scan scatter guarded by
//    one agent-acquire fence, with a second barrier between scatter and read,
//  - x_ext for step t+1 is prefetched into registers before the barrier.

constexpr int RR = 4;

// --------------------------------------------------------------- setup -----
__global__ void setup_kernel(const int* __restrict__ post, const int* __restrict__ rc,
                             int* __restrict__ slot, float* __restrict__ rec,
                             unsigned long long* __restrict__ mask,
                             unsigned long long* __restrict__ barr,
                             unsigned* __restrict__ release,
                             int E, int N, int nmask, int nbar) {
    int i = blockIdx.x * blockDim.x + threadIdx.x;
    if (i < E) slot[i] = post[i] * RR + rc[i];
    if (i < 4 * N) rec[i] = 0.f;
    if (i < nmask) mask[i] = 0ull;
    if (i < nbar * 8) barr[i] = 0ull;       // one u64 per 64B
    if (i < nbar * 16) release[i] = 0u;     // one u32 per 64B
}

// ------------------------------------------------------- grid barrier ------
// Returns the global number of spiking blocks for this event (from the low
// word of the arrival counter). Caller must have drained any ops that need
// cross-block visibility (per wave) BEFORE calling.
__device__ __forceinline__ int gbar(unsigned long long* __restrict__ barr,
                                    unsigned* __restrict__ release,
                                    int bslot, bool master, unsigned nblk,
                                    int* s_blkspk, int* s_spk) {
    __syncthreads();                         // all waves arrived, LDS flag visible
    if (threadIdx.x == 0) {
        int blk = *s_blkspk;
        *s_blkspk = 0;
        unsigned long long add = (1ull << 32) | (unsigned long long)(blk ? 1u : 0u);
        __hip_atomic_fetch_add(&barr[(size_t)bslot * 8], add,
                               __ATOMIC_RELAXED, __HIP_MEMORY_SCOPE_AGENT);
        unsigned rel;
        if (master) {
            for (;;) {
                unsigned long long v = __hip_atomic_load(&barr[(size_t)bslot * 8],
                                        __ATOMIC_RELAXED, __HIP_MEMORY_SCOPE_AGENT);
                if ((unsigned)(v >> 32) >= nblk) { rel = (unsigned)v + 1u; break; }
                __builtin_amdgcn_s_sleep(2);
            }
            __hip_atomic_store(&release[(size_t)bslot * 16], rel,
                               __ATOMIC_RELAXED, __HIP_MEMORY_SCOPE_AGENT);
        } else {
            for (;;) {
                rel = __hip_atomic_load(&release[(size_t)bslot * 16],
                                        __ATOMIC_RELAXED, __HIP_MEMORY_SCOPE_AGENT);
                if (rel) break;
                __builtin_amdgcn_s_sleep(16);
            }
        }
        *s_spk = (int)(rel - 1u);
    }
    __syncthreads();
    return *s_spk;
}

// ----------------------------------------------------------- sim kernel ----
__global__ void __launch_bounds__(1024)
sim_kernel(const float* __restrict__ x_ext,
           const float* __restrict__ v0,
           const float* __restrict__ v_th,
           const float* __restrict__ v_rst,
           const float* __restrict__ t_rf,
           const float* __restrict__ decay,
           const float* __restrict__ curf,
           const float* __restrict__ e_l,
           const float2* __restrict__ aamps,
           const float2* __restrict__ adec,
           const float* __restrict__ syn_d,
           const float* __restrict__ psc_i,
           const int* __restrict__ pre,
           const int* __restrict__ slot,
           const float* __restrict__ w_rec,
           float* __restrict__ rec,
           unsigned long long* __restrict__ mask,
           unsigned long long* __restrict__ barr,
           unsigned* __restrict__ release,
           float* __restrict__ out,
           int E, int N, int T)
{
    const int gtid = blockIdx.x * blockDim.x + threadIdx.x;
    const int nth  = gridDim.x * blockDim.x;
    const bool own = gtid < N;
    const bool master = (blockIdx.x == 0);
    const unsigned nblk = gridDim.x;

    __shared__ int s_blkspk;
    __shared__ int s_spk;
    if (threadIdx.x == 0) { s_blkspk = 0; s_spk = 0; }
    __syncthreads();

    // ---- per-neuron state + params in registers for the whole run ----
    float psc0 = 0.f, psc1 = 0.f, psc2 = 0.f, psc3 = 0.f;
    float pr0 = 0.f, pr1 = 0.f, pr2 = 0.f, pr3 = 0.f;
    float vv = 0.f, rr = 0.f, zz = 0.f, a0 = 0.f, a1 = 0.f;
    float vth = 1.f, vrst = 0.f, trf = 0.f, dec = 0.f, cf = 0.f, el = 0.f;
    float aa0 = 0.f, aa1 = 0.f, ad0 = 0.f, ad1 = 0.f;
    if (own) {
        vv  = v0[gtid];
        vth = v_th[gtid];  vrst = v_rst[gtid];
        trf = t_rf[gtid];  dec  = decay[gtid];
        cf  = curf[gtid];  el   = e_l[gtid];
        float2 aa = aamps[gtid]; aa0 = aa.x; aa1 = aa.y;
        float2 ad = adec[gtid];  ad0 = ad.x; ad1 = ad.y;
    }
    const float sd0 = syn_d[0], sd1 = syn_d[1], sd2 = syn_d[2], sd3 = syn_d[3];
    const float pi0 = psc_i[0], pi1 = psc_i[1], pi2 = psc_i[2], pi3 = psc_i[3];

    // prefetch x_ext for t = 0
    float4 xt = own ? ((const float4*)x_ext)[gtid] : make_float4(0.f, 0.f, 0.f, 0.f);

    int prevspk = 0;       // did step t-1 spike anywhere (global)?
    int bslot = 0;
    const int E4 = E >> 2;

    for (int t = 0; t < T; ++t) {
        float ri0 = 0.f, ri1 = 0.f, ri2 = 0.f, ri3 = 0.f;

        if (prevspk) {
            // masks were written uncached by other XCDs -> invalidate so the
            // cached scan below reads fresh lines from MALL (once per spiking
            // step, NOT per poll — round-1 lesson).
            __builtin_amdgcn_fence(__ATOMIC_ACQUIRE, "agent");

            // full-E bitmask-gated scatter of step t-1 spikes
            for (int q = gtid; q < E4; q += nth) {
                const int e0 = q << 2;
                int4 p = *(const int4*)(pre + e0);
                bool b0 = (mask[p.x >> 6] >> (p.x & 63)) & 1ull;
                bool b1 = (mask[p.y >> 6] >> (p.y & 63)) & 1ull;
                bool b2 = (mask[p.z >> 6] >> (p.z & 63)) & 1ull;
                bool b3 = (mask[p.w >> 6] >> (p.w & 63)) & 1ull;
                if (b0 | b1 | b2 | b3) {
                    int4 s = *(const int4*)(slot + e0);
                    float4 ww = *(const float4*)(w_rec + e0);
                    if (b0) __hip_atomic_fetch_add(rec + s.x, ww.x, __ATOMIC_RELAXED, __HIP_MEMORY_SCOPE_AGENT);
                    if (b1) __hip_atomic_fetch_add(rec + s.y, ww.y, __ATOMIC_RELAXED, __HIP_MEMORY_SCOPE_AGENT);
                    if (b2) __hip_atomic_fetch_add(rec + s.z, ww.z, __ATOMIC_RELAXED, __HIP_MEMORY_SCOPE_AGENT);
                    if (b3) __hip_atomic_fetch_add(rec + s.w, ww.w, __ATOMIC_RELAXED, __HIP_MEMORY_SCOPE_AGENT);
                }
            }
            if (gtid == 0) {
                for (int e = E & ~3; e < E; ++e) {
                    int p = pre[e];
                    if ((mask[p >> 6] >> (p & 63)) & 1ull)
                        __hip_atomic_fetch_add(rec + slot[e], w_rec[e],
                                               __ATOMIC_RELAXED, __HIP_MEMORY_SCOPE_AGENT);
                }
            }
            // scatter must land before any block reads rec
            asm volatile("s_waitcnt vmcnt(0)" ::: "memory");
            (void)gbar(barr, release, bslot, master, nblk, &s_blkspk, &s_spk);
            ++bslot;

            // read own 4 slots (MALL-coherent) + restore zero invariant
            if (own) {
                unsigned long long* rp = (unsigned long long*)(rec + (size_t)4 * gtid);
                unsigned long long lo = __hip_atomic_load(rp,     __ATOMIC_RELAXED, __HIP_MEMORY_SCOPE_AGENT);
                unsigned long long hi = __hip_atomic_load(rp + 1, __ATOMIC_RELAXED, __HIP_MEMORY_SCOPE_AGENT);
                __hip_atomic_store(rp,     0ull, __ATOMIC_RELAXED, __HIP_MEMORY_SCOPE_AGENT);
                __hip_atomic_store(rp + 1, 0ull, __ATOMIC_RELAXED, __HIP_MEMORY_SCOPE_AGENT);
                ri0 = __uint_as_float((unsigned)lo);
                ri1 = __uint_as_float((unsigned)(lo >> 32));
                ri2 = __uint_as_float((unsigned)hi);
                ri3 = __uint_as_float((unsigned)(hi >> 32));
            }
        }

        // ---------------- neuron update (state in registers) ---------------
        float nz = 0.f;
        if (own) {
            float i0 = ri0 + xt.x, i1 = ri1 + xt.y, i2 = ri2 + xt.z, i3 = ri3 + xt.w;
            float npr0 = pr0 * sd0 + i0 * pi0;
            float npr1 = pr1 * sd1 + i1 * pi1;
            float npr2 = pr2 * sd2 + i2 * pi2;
            float npr3 = pr3 * sd3 + i3 * pi3;
            float npc0 = psc0 * sd0 + sd0 * pr0;   // OLD psc_rise, DT=1
            float npc1 = psc1 * sd1 + sd1 * pr1;
            float npc2 = psc2 * sd2 + sd2 * pr2;
            float npc3 = psc3 * sd3 + sd3 * pr3;
            float in_cur = npc0 + npc1 + npc2 + npc3;
            psc0 = npc0; psc1 = npc1; psc2 = npc2; psc3 = npc3;
            pr0 = npr0; pr1 = npr1; pr2 = npr2; pr3 = npr3;

            float asum = a0 + a1;                  // OLD asc sum
            a0 = ad0 * a0 + zz * aa0;
            a1 = ad1 * a1 + zz * aa1;

            float nv  = dec * vv + cf * (in_cur + asum + el) + zz * (vrst - vth);
            float vsc = (nv - vth) / vth;
            nz = (vsc > 0.f) ? 1.f : 0.f;
            if (rr > 0.f) nz = 0.f;                // refractory mask (OLD r)
            rr = fmaxf(rr - 1.f + nz * trf, 0.f);
            vv = nv; zz = nz;
            out[(size_t)t * N + gtid] = nz;        // cached store, flushed at exit
        }

        // prefetch x_ext for t+1 (consumed after the barrier -> latency hidden)
        float4 xtn = (own && t + 1 < T)
                   ? ((const float4*)x_ext)[(size_t)(t + 1) * N + gtid]
                   : make_float4(0.f, 0.f, 0.f, 0.f);

        // publish spike bitmask. Lazy-refresh invariant: a wave stores its
        // ballot iff it spiked now OR the previous step spiked globally (this
        // clears any stale nonzero word before the next possible scan).
        unsigned long long bal = __ballot(nz > 0.f);
        if ((threadIdx.x & 63) == 0) {
            if (bal != 0ull) s_blkspk = 1;                      // benign race
            if (gtid < N && (bal != 0ull || prevspk))
                __hip_atomic_store(&mask[gtid >> 6], bal,
                                   __ATOMIC_RELAXED, __HIP_MEMORY_SCOPE_AGENT);
        }
        // drain only when we produced cross-block-visible ops this step
        // (mask stores / rec zero-stores). Wave-uniform condition.
        if (bal != 0ull || prevspk)
            asm volatile("s_waitcnt vmcnt(0)" ::: "memory");

        if (t + 1 < T) {
            prevspk = gbar(barr, release, bslot, master, nblk, &s_blkspk, &s_spk);
            ++bslot;
        }
        xt = xtn;
    }
}

// --------------------------------------------------------------- launch ----
extern "C" void kernel_launch(void* const* d_in, const int* in_sizes, int n_in,
                              void* d_out, int out_size, void* d_ws, size_t ws_size,
                              hipStream_t stream) {
    const float* w_rec = (const float*)d_in[0];
    const float* x_ext = (const float*)d_in[1];
    const float* v0    = (const float*)d_in[2];
    const float* v_th  = (const float*)d_in[3];
    const float* v_rst = (const float*)d_in[4];
    const float* t_rf  = (const float*)d_in[5];
    const float* decay = (const float*)d_in[6];
    const float* curf  = (const float*)d_in[7];
    const float* e_l   = (const float*)d_in[8];
    const float* aamps = (const float*)d_in[9];
    const float* adec  = (const float*)d_in[10];
    const float* syn_d = (const float*)d_in[11];
    const float* psc_i = (const float*)d_in[12];
    const int*   pre   = (const int*)d_in[13];
    const int*   post  = (const int*)d_in[14];
    const int*   rc    = (const int*)d_in[15];

    const int E = in_sizes[0];
    const int N = in_sizes[2];            // B == 1
    const int T = in_sizes[1] / (N * RR);
    const int nmask = (N + 63) / 64;
    const int nbar  = 2 * T + 4;          // one 64B slot per barrier event

    // -------- workspace layout (all offsets 16B-aligned) --------
    float* wf = (float*)d_ws;
    float* rec = wf;                                            // 4N floats
    int*   slot = (int*)(wf + (size_t)4 * N);                   // E ints
    unsigned long long* mask = (unsigned long long*)(wf + (size_t)4 * N + E);  // nmask u64
    unsigned long long* barr = mask + nmask;                    // nbar*8 u64
    unsigned* release = (unsigned*)(barr + (size_t)nbar * 8);   // nbar*16 u32

    const int setup_n = E;  // E >= 4N, nmask, nbar*16 for this problem
    setup_kernel<<<(setup_n + 255) / 256, 256, 0, stream>>>(
        post, rc, slot, rec, mask, barr, release, E, N, nmask, nbar);

    const int BS = 1024;
    const int nblk = (N + BS - 1) / BS;   // 98 blocks @ N=100000 -> guaranteed
                                          // co-resident on 256 CUs (16 waves/CU)
    sim_kernel<<<nblk, BS, 0, stream>>>(
        x_ext, v0, v_th, v_rst, t_rf, decay, curf, e_l,
        (const float2*)aamps, (const float2*)adec, syn_d, psc_i,
        pre, slot, w_rec, rec, mask, barr, release,
        (float*)d_out, E, N, T);
}

// Round 4
// 1320.614 us; speedup vs baseline: 1.3056x; 1.3056x over previous
//
#include <hip/hip_runtime.h>

// Billeh column GLIF forward — one fused gather+update kernel per timestep.
//
// Rounds 1-3 post-mortem: persistent-kernel grid barriers cost >=10us/event on
// gfx950 (MALL round-trip chains + poll quantization), and the network spikes
// EVERY step (WRITE_SIZE evidence), so event-skipping never pays. This version
// returns to the round-0 multi-kernel structure (best measured: 926us) and
// removes its scatter kernel: recurrent input is computed by GATHER over a
// CSR sorted by post-neuron, gated by the previous step's 12.5KB spike bitmask
// staged in LDS. One kernel per step, no atomics, kernel boundary = sync.

constexpr int RR = 4;

// ---------------- setup: state init + param packing ----------------
__global__ void init_state_kernel(const float* __restrict__ v0,
                                  const float* __restrict__ v_th,
                                  const float* __restrict__ v_rst,
                                  const float* __restrict__ t_rf,
                                  const float* __restrict__ decay,
                                  const float* __restrict__ curf,
                                  const float* __restrict__ e_l,
                                  const float2* __restrict__ aamps,
                                  const float2* __restrict__ adec,
                                  float4* __restrict__ psc,
                                  float4* __restrict__ psc_rise,
                                  float* __restrict__ v, float* __restrict__ r,
                                  float2* __restrict__ asc,
                                  float4* __restrict__ p0, float4* __restrict__ p1,
                                  float2* __restrict__ p2,
                                  unsigned long long* __restrict__ maskA,
                                  unsigned long long* __restrict__ maskB,
                                  int* __restrict__ hist, int* __restrict__ cursor,
                                  int N, int nmask) {
    int i = blockIdx.x * blockDim.x + threadIdx.x;
    if (i < N) {
        psc[i] = make_float4(0.f, 0.f, 0.f, 0.f);
        psc_rise[i] = make_float4(0.f, 0.f, 0.f, 0.f);
        v[i] = v0[i]; r[i] = 0.f;
        asc[i] = make_float2(0.f, 0.f);
        p0[i] = make_float4(v_th[i], v_rst[i], t_rf[i], decay[i]);
        float2 aa = aamps[i];
        p1[i] = make_float4(curf[i], e_l[i], aa.x, aa.y);
        p2[i] = adec[i];
        hist[i] = 0; cursor[i] = 0;
    }
    if (i < nmask) { maskA[i] = 0ull; maskB[i] = 0ull; }
}

// ---------------- CSR-by-post build ----------------
__global__ void hist_kernel(const int* __restrict__ post, int* __restrict__ hist, int E) {
    int stride = gridDim.x * blockDim.x;
    for (int e = blockIdx.x * blockDim.x + threadIdx.x; e < E; e += stride)
        atomicAdd(&hist[post[e]], 1);
}

__global__ void scan_kernel(const int* __restrict__ hist, int* __restrict__ loc,
                            int* __restrict__ blocksum, int N) {
    __shared__ int s[1024];
    int n = blockIdx.x * 1024 + threadIdx.x;
    int vv = (n < N) ? hist[n] : 0;
    s[threadIdx.x] = vv;
    __syncthreads();
    for (int off = 1; off < 1024; off <<= 1) {
        int t = (threadIdx.x >= (unsigned)off) ? s[threadIdx.x - off] : 0;
        __syncthreads();
        s[threadIdx.x] += t;
        __syncthreads();
    }
    if (n < N) loc[n] = s[threadIdx.x] - vv;     // exclusive within block
    if (threadIdx.x == 1023) blocksum[blockIdx.x] = s[1023];
}

__global__ void topscan_kernel(const int* __restrict__ blocksum,
                               int* __restrict__ blockpref, int NB) {
    __shared__ int s[256];
    if (NB > 256) {
        if (threadIdx.x == 0) { int acc = 0; for (int b = 0; b < NB; b++) { blockpref[b] = acc; acc += blocksum[b]; } }
        return;
    }
    int vv = ((int)threadIdx.x < NB) ? blocksum[threadIdx.x] : 0;
    s[threadIdx.x] = vv;
    __syncthreads();
    for (int off = 1; off < 256; off <<= 1) {
        int t = (threadIdx.x >= (unsigned)off) ? s[threadIdx.x - off] : 0;
        __syncthreads();
        s[threadIdx.x] += t;
        __syncthreads();
    }
    if ((int)threadIdx.x < NB) blockpref[threadIdx.x] = s[threadIdx.x] - vv;
}

__global__ void rowptr_kernel(const int* __restrict__ loc,
                              const int* __restrict__ blockpref,
                              int* __restrict__ rowstart, int N, int E) {
    int n = blockIdx.x * blockDim.x + threadIdx.x;
    if (n < N) rowstart[n] = blockpref[n >> 10] + loc[n];
    if (n == 0) rowstart[N] = E;
}

// edges grouped by post-neuron; payload = {pre | rc<<30, w}
__global__ void fill_kernel(const int* __restrict__ pre, const int* __restrict__ post,
                            const int* __restrict__ rc, const float* __restrict__ w,
                            const int* __restrict__ rowstart, int* __restrict__ cursor,
                            uint2* __restrict__ edges, int E) {
    int stride = gridDim.x * blockDim.x;
    for (int e = blockIdx.x * blockDim.x + threadIdx.x; e < E; e += stride) {
        int pn = post[e];
        int k = atomicAdd(&cursor[pn], 1);
        edges[rowstart[pn] + k] = make_uint2((unsigned)pre[e] | ((unsigned)rc[e] << 30),
                                             __float_as_uint(w[e]));
    }
}

// ---------------- per-step fused gather + neuron update ----------------
__global__ void __launch_bounds__(512)
step_kernel(const float4* __restrict__ x_t,
            const uint2* __restrict__ edges,
            const int* __restrict__ rowstart,
            const unsigned long long* __restrict__ mask_in,
            unsigned long long* __restrict__ mask_out,
            float4* __restrict__ psc,
            float4* __restrict__ psc_rise,
            float* __restrict__ v, float* __restrict__ r,
            float2* __restrict__ asc,
            const float4* __restrict__ p0,   // vth, vrst, tref, decay
            const float4* __restrict__ p1,   // curf, e_l, aa0, aa1
            const float2* __restrict__ p2,   // ad0, ad1
            const float* __restrict__ syn_d4,
            const float* __restrict__ psc_i4,
            float* __restrict__ out_t,
            int N, int nmask)
{
    extern __shared__ unsigned long long smask[];
    __shared__ int s_any;
    const int tid = threadIdx.x;
    const int n = blockIdx.x * blockDim.x + tid;
    const bool own = n < N;

    if (tid == 0) s_any = 0;
    __syncthreads();
    // stage previous-step spike bitmask into LDS; OR-reduce for quiet skip
    bool any = false;
    for (int i = tid; i < nmask; i += blockDim.x) {
        unsigned long long m = mask_in[i];
        smask[i] = m;
        any |= (m != 0ull);
    }
    if (any) s_any = 1;                      // benign race
    __syncthreads();
    const int anyspk = s_any;

    // issue x_t load early; consumed after the gather loop
    float4 xt = own ? x_t[n] : make_float4(0.f, 0.f, 0.f, 0.f);

    // ---- gather recurrent input from incoming edges (bitmask-gated) ----
    float acc0 = 0.f, acc1 = 0.f, acc2 = 0.f, acc3 = 0.f;
    if (anyspk && own) {
        const int s = rowstart[n], e = rowstart[n + 1];
        for (int j = s; j < e; ++j) {
            uint2 ed = edges[j];
            unsigned p = ed.x & 0x3FFFFFFFu;
            if ((smask[p >> 6] >> (p & 63)) & 1ull) {
                unsigned rcv = ed.x >> 30;
                float wv = __uint_as_float(ed.y);
                acc0 += (rcv == 0u) ? wv : 0.f;
                acc1 += (rcv == 1u) ? wv : 0.f;
                acc2 += (rcv == 2u) ? wv : 0.f;
                acc3 += (rcv == 3u) ? wv : 0.f;
            }
        }
    }

    // ---- neuron update ----
    float nz = 0.f;
    if (own) {
        const float sd0 = syn_d4[0], sd1 = syn_d4[1], sd2 = syn_d4[2], sd3 = syn_d4[3];
        const float pi0 = psc_i4[0], pi1 = psc_i4[1], pi2 = psc_i4[2], pi3 = psc_i4[3];

        float zz = (float)((smask[n >> 6] >> (n & 63)) & 1ull);   // previous spike

        float4 pr = psc_rise[n];
        float4 pc = psc[n];
        float i0 = acc0 + xt.x, i1 = acc1 + xt.y, i2 = acc2 + xt.z, i3 = acc3 + xt.w;
        float npr0 = pr.x * sd0 + i0 * pi0;
        float npr1 = pr.y * sd1 + i1 * pi1;
        float npr2 = pr.z * sd2 + i2 * pi2;
        float npr3 = pr.w * sd3 + i3 * pi3;
        float npc0 = pc.x * sd0 + sd0 * pr.x;    // OLD psc_rise, DT=1
        float npc1 = pc.y * sd1 + sd1 * pr.y;
        float npc2 = pc.z * sd2 + sd2 * pr.z;
        float npc3 = pc.w * sd3 + sd3 * pr.w;
        float in_cur = npc0 + npc1 + npc2 + npc3;
        psc_rise[n] = make_float4(npr0, npr1, npr2, npr3);
        psc[n]      = make_float4(npc0, npc1, npc2, npc3);

        float2 a  = asc[n];
        float asum = a.x + a.y;                  // OLD asc sum
        float4 P0 = p0[n];                       // vth, vrst, tref, decay
        float4 P1 = p1[n];                       // curf, e_l, aa0, aa1
        float2 ad = p2[n];
        asc[n] = make_float2(ad.x * a.x + zz * P1.z, ad.y * a.y + zz * P1.w);

        float vth = P0.x;
        float vv  = P0.w * v[n] + P1.x * (in_cur + asum + P1.y) + zz * (P0.y - vth);
        float vsc = (vv - vth) / vth;
        float rn  = r[n];
        nz = (vsc > 0.f) ? 1.f : 0.f;
        if (rn > 0.f) nz = 0.f;                  // refractory mask (OLD r)
        float nr  = fmaxf(rn - 1.f + nz * P0.z, 0.f);

        v[n] = vv;
        r[n] = nr;
        out_t[n] = nz;
    }

    // publish this step's spike bitmask (one store per wave, no atomics)
    unsigned long long bal = __ballot(nz > 0.f);
    if (own && (tid & 63) == 0) mask_out[n >> 6] = bal;
}

// ---------------- launch ----------------
extern "C" void kernel_launch(void* const* d_in, const int* in_sizes, int n_in,
                              void* d_out, int out_size, void* d_ws, size_t ws_size,
                              hipStream_t stream) {
    const float* w_rec = (const float*)d_in[0];
    const float* x_ext = (const float*)d_in[1];
    const float* v0    = (const float*)d_in[2];
    const float* v_th  = (const float*)d_in[3];
    const float* v_rst = (const float*)d_in[4];
    const float* t_rf  = (const float*)d_in[5];
    const float* decay = (const float*)d_in[6];
    const float* curf  = (const float*)d_in[7];
    const float* e_l   = (const float*)d_in[8];
    const float* aamps = (const float*)d_in[9];
    const float* adec  = (const float*)d_in[10];
    const float* syn_d = (const float*)d_in[11];
    const float* psc_i = (const float*)d_in[12];
    const int*   pre   = (const int*)d_in[13];
    const int*   post  = (const int*)d_in[14];
    const int*   rc    = (const int*)d_in[15];

    const int E = in_sizes[0];
    const int N = in_sizes[2];            // B == 1
    const int T = in_sizes[1] / (N * RR);
    const int nmask = (N + 63) / 64;
    const int NB = (N + 1023) / 1024;

    // -------- workspace layout (bytes; float4 arrays first for 16B align) ----
    char* ws = (char*)d_ws;
    float4* psc      = (float4*)ws;                       ws += (size_t)N * 16;
    float4* psc_rise = (float4*)ws;                       ws += (size_t)N * 16;
    float4* p0       = (float4*)ws;                       ws += (size_t)N * 16;
    float4* p1       = (float4*)ws;                       ws += (size_t)N * 16;
    float2* p2       = (float2*)ws;                       ws += (size_t)N * 8;
    float2* asc      = (float2*)ws;                       ws += (size_t)N * 8;
    float*  v        = (float*)ws;                        ws += (size_t)N * 4;
    float*  r        = (float*)ws;                        ws += (size_t)N * 4;
    uint2*  edges    = (uint2*)ws;                        ws += (size_t)E * 8;
    unsigned long long* maskA = (unsigned long long*)ws;  ws += (size_t)nmask * 8;
    unsigned long long* maskB = (unsigned long long*)ws;  ws += (size_t)nmask * 8;
    int* rowstart    = (int*)ws;                          ws += (size_t)(N + 1) * 4;
    int* hist        = (int*)ws;                          ws += (size_t)N * 4;
    int* loc         = (int*)ws;                          ws += (size_t)N * 4;
    int* cursor      = (int*)ws;                          ws += (size_t)N * 4;
    int* blocksum    = (int*)ws;                          ws += (size_t)NB * 4;
    int* blockpref   = (int*)ws;                          /* +NB*4 */

    // -------- one-time setup (6 small dispatches) --------
    init_state_kernel<<<(N + 255) / 256, 256, 0, stream>>>(
        v0, v_th, v_rst, t_rf, decay, curf, e_l,
        (const float2*)aamps, (const float2*)adec,
        psc, psc_rise, v, r, asc, p0, p1, p2, maskA, maskB, hist, cursor, N, nmask);
    hist_kernel<<<2048, 256, 0, stream>>>(post, hist, E);
    scan_kernel<<<NB, 1024, 0, stream>>>(hist, loc, blocksum, N);
    topscan_kernel<<<1, 256, 0, stream>>>(blocksum, blockpref, NB);
    rowptr_kernel<<<(N + 255) / 256, 256, 0, stream>>>(loc, blockpref, rowstart, N, E);
    fill_kernel<<<2048, 256, 0, stream>>>(pre, post, rc, w_rec, rowstart, cursor, edges, E);

    // -------- T fused steps; double-buffered spike bitmask --------
    const int BS = 512;
    const int nblk = (N + BS - 1) / BS;
    const size_t smbytes = (size_t)nmask * 8;   // 12.5 KB @ N=100000
    for (int t = 0; t < T; ++t) {
        const unsigned long long* min_ = (t & 1) ? maskB : maskA;
        unsigned long long* mout = (t & 1) ? maskA : maskB;
        step_kernel<<<nblk, BS, smbytes, stream>>>(
            (const float4*)(x_ext + (size_t)t * N * RR),
            edges, rowstart, min_, mout,
            psc, psc_rise, v, r, asc, p0, p1, p2,
            syn_d, psc_i, (float*)d_out + (size_t)t * N, N, nmask);
    }
}